// Round 1
// baseline (1949.236 us; speedup 1.0000x reference)
//
#include <hip/hip_runtime.h>
#include <hip/hip_bf16.h>

// Problem constants fixed by setup_inputs()
#define NNODE   20000
#define BS      8
#define NEG1    33
#define DDIM    32
#define NLAYER  6
#define NRELX2  128     // 2*N_REL
#define FEAT    256     // BS*DDIM
#define INW     416     // 13*DDIM

// ---------------------------------------------------------------- precompute
__global__ void count_kernel(const int* __restrict__ es, const int* __restrict__ ed,
                             int* __restrict__ cnt, int E) {
    int i = blockIdx.x * 256 + threadIdx.x;
    if (i >= 2 * E) return;
    int dst = (i < E) ? ed[i] : es[i - E];
    atomicAdd(&cnt[dst], 1);
}

__global__ void scan_kernel(const int* __restrict__ cnt, int* __restrict__ row_ptr, int N) {
    __shared__ int sh[1024];
    __shared__ int s_carry;
    if (threadIdx.x == 0) { s_carry = 0; row_ptr[0] = 0; }
    __syncthreads();
    for (int base = 0; base < N; base += 1024) {
        int i = base + threadIdx.x;
        int v = (i < N) ? cnt[i] : 0;
        sh[threadIdx.x] = v;
        __syncthreads();
        for (int off = 1; off < 1024; off <<= 1) {
            int t = (threadIdx.x >= off) ? sh[threadIdx.x - off] : 0;
            __syncthreads();
            sh[threadIdx.x] += t;
            __syncthreads();
        }
        int carry = s_carry;
        if (i < N) row_ptr[i + 1] = carry + sh[threadIdx.x];
        __syncthreads();
        if (threadIdx.x == 1023) s_carry = carry + sh[1023];
        __syncthreads();
    }
}

__global__ void fill_kernel(const int* __restrict__ es, const int* __restrict__ ed,
                            const int* __restrict__ et, const int* __restrict__ row_ptr,
                            int* __restrict__ cursor, int* __restrict__ csr_src,
                            int* __restrict__ csr_et, int E) {
    int i = blockIdx.x * 256 + threadIdx.x;
    if (i >= 2 * E) return;
    int src, dst, ty;
    if (i < E) { src = es[i]; dst = ed[i]; ty = et[i]; }
    else       { src = ed[i - E]; dst = es[i - E]; ty = et[i - E] + 64; }
    int pos = row_ptr[dst] + atomicAdd(&cursor[dst], 1);
    csr_src[pos] = src;
    csr_et[pos]  = ty;
}

__global__ void deg_kernel(const int* __restrict__ cnt, float* __restrict__ dinv,
                           float* __restrict__ logdeg, int N) {
    int n = blockIdx.x * 256 + threadIdx.x;
    if (n >= N) return;
    float deg = (float)cnt[n] + 1.0f;
    dinv[n] = 1.0f / deg;
    logdeg[n] = logf(deg);
}

__global__ void mean_kernel(const float* __restrict__ logdeg, float* __restrict__ meanout, int N) {
    __shared__ float sh[256];
    float s = 0.f;
    for (int i = threadIdx.x; i < N; i += 256) s += logdeg[i];
    sh[threadIdx.x] = s;
    __syncthreads();
    for (int off = 128; off > 0; off >>= 1) {
        if (threadIdx.x < off) sh[threadIdx.x] += sh[threadIdx.x + off];
        __syncthreads();
    }
    if (threadIdx.x == 0) meanout[0] = sh[0] / (float)N;
}

__global__ void sc_kernel(const float* __restrict__ logdeg, const float* __restrict__ meanp,
                          float* __restrict__ sc, int N) {
    int n = blockIdx.x * 256 + threadIdx.x;
    if (n >= N) return;
    sc[n] = logdeg[n] / meanp[0];
}

__global__ void prep_kernel(const int* __restrict__ h_index, const int* __restrict__ t_index,
                            const int* __restrict__ r_index, const float* __restrict__ rel_query,
                            int* __restrict__ h0, int* __restrict__ r0,
                            float* __restrict__ query, int* __restrict__ tnew) {
    __shared__ int s_isneg[BS];
    __shared__ int s_r0[BS];
    int t = threadIdx.x;
    if (t < BS) {
        int b = t;
        int hv = h_index[b * NEG1];
        int all = 1;
        for (int j = 1; j < NEG1; j++) all &= (h_index[b * NEG1 + j] == hv);
        s_isneg[b] = all;
        int h0v = all ? hv : t_index[b * NEG1];
        int r0v = all ? r_index[b * NEG1] : r_index[b * NEG1] + 64;
        s_r0[b] = r0v;
        h0[b] = h0v;
        r0[b] = r0v;
    }
    __syncthreads();
    {
        int b = t >> 5, dd = t & 31;
        query[t] = rel_query[s_r0[b] * DDIM + dd];
    }
    for (int idx = t; idx < BS * NEG1; idx += 256) {
        int b = idx / NEG1;
        tnew[idx] = s_isneg[b] ? t_index[idx] : h_index[idx];
    }
}

__global__ void rel_kernel(const float* __restrict__ rel_query, const float* __restrict__ Wrel,
                           const float* __restrict__ brel, float* __restrict__ rel_all) {
    int idx = blockIdx.x * 256 + threadIdx.x;
    if (idx >= NLAYER * NRELX2 * DDIM) return;
    int i  = idx >> 12;          // / 4096
    int q  = (idx >> 5) & 127;
    int dd = idx & 31;
    float acc = brel[i * DDIM + dd];
    #pragma unroll
    for (int k = 0; k < DDIM; k++)
        acc = fmaf(rel_query[q * DDIM + k], Wrel[i * DDIM * DDIM + k * DDIM + dd], acc);
    rel_all[idx] = acc;
}

__global__ void init_x_kernel(float* __restrict__ x, const int* __restrict__ h0,
                              const float* __restrict__ query) {
    int i = blockIdx.x * 256 + threadIdx.x;
    if (i >= NNODE * FEAT) return;
    int n = i >> 8;
    int t = i & 255;
    int b = t >> 5;
    x[i] = (h0[b] == n) ? query[t] : 0.f;
}

// ---------------------------------------------------------------- main layer
__global__ __launch_bounds__(256) void layer_kernel(
    const float* __restrict__ x_in, float* __restrict__ x_out,
    const int* __restrict__ row_ptr, const int* __restrict__ csr_src,
    const int* __restrict__ csr_et,
    const float* __restrict__ rel_i, const float* __restrict__ Wlin_i,
    const float* __restrict__ blin_i, const float* __restrict__ g_i,
    const float* __restrict__ b_i,
    const float* __restrict__ dinv, const float* __restrict__ sc,
    const int* __restrict__ h0, const float* __restrict__ query) {
    int n = blockIdx.x;
    int t = threadIdx.x;
    int b = t >> 5, dd = t & 31;
    __shared__ float s_rel[NRELX2 * DDIM];   // 16 KB
    __shared__ float s_in[BS][INW];          // 13 KB

    for (int k = t; k < NRELX2 * DDIM; k += 256) s_rel[k] = rel_i[k];

    float bval = (h0[b] == n) ? query[t] : 0.f;   // boundary (self segment entry)
    float sum = bval, sumsq = bval * bval, mx = bval, mn = bval;
    int e0 = row_ptr[n], e1 = row_ptr[n + 1];
    __syncthreads();

    for (int e = e0; e < e1; ++e) {
        int s  = csr_src[e];
        int ty = csr_et[e];
        float m = x_in[s * FEAT + t] * s_rel[ty * DDIM + dd];
        sum += m;
        sumsq += m * m;
        mx = fmaxf(mx, m);
        mn = fminf(mn, m);
    }

    float dv   = dinv[n];
    float mean = sum * dv;
    float sqm  = sumsq * dv;
    float stdv = sqrtf(fmaxf(sqm - mean * mean, 1e-6f));
    float scv  = sc[n];
    float sc2  = 1.0f / fmaxf(scv, 0.01f);
    float xv   = x_in[n * FEAT + t];

    s_in[b][dd] = xv;
    int base = DDIM + dd * 12;  // (dd*4+stat)*3+scl
    s_in[b][base + 0]  = mean;  s_in[b][base + 1]  = mean * scv; s_in[b][base + 2]  = mean * sc2;
    s_in[b][base + 3]  = mx;    s_in[b][base + 4]  = mx * scv;   s_in[b][base + 5]  = mx * sc2;
    s_in[b][base + 6]  = mn;    s_in[b][base + 7]  = mn * scv;   s_in[b][base + 8]  = mn * sc2;
    s_in[b][base + 9]  = stdv;  s_in[b][base + 10] = stdv * scv; s_in[b][base + 11] = stdv * sc2;
    __syncthreads();

    float acc = blin_i[dd];
    #pragma unroll 8
    for (int k = 0; k < INW; ++k)
        acc = fmaf(s_in[b][k], Wlin_i[k * DDIM + dd], acc);

    // LayerNorm over dd (32 lanes sharing the same b)
    float s1 = acc;
    #pragma unroll
    for (int m = 16; m >= 1; m >>= 1) s1 += __shfl_xor(s1, m);
    float lmean = s1 * (1.f / 32.f);
    float dlt = acc - lmean;
    float s2 = dlt * dlt;
    #pragma unroll
    for (int m = 16; m >= 1; m >>= 1) s2 += __shfl_xor(s2, m);
    float var = s2 * (1.f / 32.f);
    float y = dlt / sqrtf(var + 1e-5f) * g_i[dd] + b_i[dd];
    y = fmaxf(y, 0.f);
    x_out[n * FEAT + t] = y + xv;
}

// ---------------------------------------------------------------- readout
__global__ void score_kernel(const float* __restrict__ x, const int* __restrict__ tnew,
                             const float* __restrict__ query,
                             const float* __restrict__ W1, const float* __restrict__ b1,
                             const float* __restrict__ W2, const float* __restrict__ b2,
                             float* __restrict__ out) {
    int idx = blockIdx.x;         // b*33+j
    int b = idx / NEG1;
    int k = threadIdx.x;          // 0..63
    __shared__ float v[64];
    int tnode = tnew[idx];
    if (k < 32) v[k] = x[tnode * FEAT + b * DDIM + k];
    else        v[k] = query[b * DDIM + (k - 32)];
    __syncthreads();
    float acc = b1[k];
    #pragma unroll
    for (int l = 0; l < 64; l++) acc = fmaf(v[l], W1[l * 64 + k], acc);
    acc = fmaxf(acc, 0.f);
    float p = acc * W2[k];
    #pragma unroll
    for (int m = 32; m >= 1; m >>= 1) p += __shfl_xor(p, m);
    if (k == 0) out[idx] = p + b2[0];
}

// ---------------------------------------------------------------- launch
extern "C" void kernel_launch(void* const* d_in, const int* in_sizes, int n_in,
                              void* d_out, int out_size, void* d_ws, size_t ws_size,
                              hipStream_t stream) {
    const int* edge_src  = (const int*)d_in[0];
    const int* edge_dst  = (const int*)d_in[1];
    const int* edge_type = (const int*)d_in[2];
    const int* h_index   = (const int*)d_in[3];
    const int* t_index   = (const int*)d_in[4];
    const int* r_index   = (const int*)d_in[5];
    const float* rel_query = (const float*)d_in[7];
    const float* Wrel    = (const float*)d_in[8];
    const float* brel    = (const float*)d_in[9];
    const float* Wlin    = (const float*)d_in[10];
    const float* blin    = (const float*)d_in[11];
    const float* ln_g    = (const float*)d_in[12];
    const float* ln_b    = (const float*)d_in[13];
    const float* W1      = (const float*)d_in[14];
    const float* b1      = (const float*)d_in[15];
    const float* W2      = (const float*)d_in[16];
    const float* b2      = (const float*)d_in[17];

    const int N  = NNODE;
    const int E  = in_sizes[0];
    const int E2 = 2 * E;

    char* p = (char*)d_ws;
    auto carve = [&](size_t bytes) {
        void* r = (void*)p;
        p += (bytes + 255) & ~(size_t)255;
        return r;
    };
    float* x0      = (float*)carve((size_t)N * FEAT * 4);
    float* x1      = (float*)carve((size_t)N * FEAT * 4);
    int*   cnt     = (int*)carve((size_t)N * 4);
    int*   row_ptr = (int*)carve((size_t)(N + 1) * 4);
    int*   cursor  = (int*)carve((size_t)N * 4);
    int*   csr_src = (int*)carve((size_t)E2 * 4);
    int*   csr_et  = (int*)carve((size_t)E2 * 4);
    float* dinv    = (float*)carve((size_t)N * 4);
    float* logdeg  = (float*)carve((size_t)N * 4);
    float* scn     = (float*)carve((size_t)N * 4);
    float* meanp   = (float*)carve(16);
    float* rel_all = (float*)carve((size_t)NLAYER * NRELX2 * DDIM * 4);
    int*   h0      = (int*)carve(BS * 4);
    int*   r0      = (int*)carve(BS * 4);
    float* query   = (float*)carve(BS * DDIM * 4);
    int*   tnew    = (int*)carve(BS * NEG1 * 4);

    hipMemsetAsync(cnt, 0, (size_t)N * 4, stream);
    hipMemsetAsync(cursor, 0, (size_t)N * 4, stream);

    int eb = (E2 + 255) / 256;
    count_kernel<<<eb, 256, 0, stream>>>(edge_src, edge_dst, cnt, E);
    scan_kernel<<<1, 1024, 0, stream>>>(cnt, row_ptr, N);
    fill_kernel<<<eb, 256, 0, stream>>>(edge_src, edge_dst, edge_type, row_ptr,
                                        cursor, csr_src, csr_et, E);
    deg_kernel<<<(N + 255) / 256, 256, 0, stream>>>(cnt, dinv, logdeg, N);
    mean_kernel<<<1, 256, 0, stream>>>(logdeg, meanp, N);
    sc_kernel<<<(N + 255) / 256, 256, 0, stream>>>(logdeg, meanp, scn, N);
    prep_kernel<<<1, 256, 0, stream>>>(h_index, t_index, r_index, rel_query,
                                       h0, r0, query, tnew);
    rel_kernel<<<(NLAYER * NRELX2 * DDIM + 255) / 256, 256, 0, stream>>>(
        rel_query, Wrel, brel, rel_all);
    init_x_kernel<<<(N * FEAT + 255) / 256, 256, 0, stream>>>(x0, h0, query);

    float* xin = x0;
    float* xout = x1;
    for (int i = 0; i < NLAYER; ++i) {
        layer_kernel<<<N, 256, 0, stream>>>(
            xin, xout, row_ptr, csr_src, csr_et,
            rel_all + (size_t)i * NRELX2 * DDIM,
            Wlin + (size_t)i * INW * DDIM,
            blin + (size_t)i * DDIM,
            ln_g + (size_t)i * DDIM,
            ln_b + (size_t)i * DDIM,
            dinv, scn, h0, query);
        float* tmp = xin; xin = xout; xout = tmp;
    }

    score_kernel<<<BS * NEG1, 64, 0, stream>>>(xin, tnew, query, W1, b1, W2, b2,
                                               (float*)d_out);
}